// Round 5
// baseline (225.496 us; speedup 1.0000x reference)
//
#include <hip/hip_runtime.h>
#include <math.h>

#define TOKENS    1024
#define IN_W      512
#define BLOCK_H   256
#define OUT_W     512
#define N_EXPERTS 64
#define TOPK      2
#define NSLOTS    (TOKENS * TOPK)
#define LIST_CAP  128     // ne ~ Binom(2048,1/64): mean 32, sigma 5.6; 128 is +17 sigma
#define T_CAP     12      // max tokens per pass (covers ne <= 48 in one pass, 99.8%)
#define NGRP      4       // groups per expert -> grid 256 = 1 block/CU
#define XPAD      512     // x row stride (reads are 16-consecutive-float; no pad needed)
#define VPAD      256     // v row stride

// weight streaming through LDS (double-buffered 32 KB chunks)
#define WCHUNK_BYTES  32768
#define WCHUNK_FLOATS 8192
#define W1_NCHUNK     16   // 512 rows / 32 rows-per-chunk   (row = 1024 B)
#define W2_NCHUNK     16   // 256 rows / 16 rows-per-chunk   (row = 2048 B)

// ---------------------------------------------------------------------------
// Routing + fused compaction (verified; also zeroes `out`).
// ---------------------------------------------------------------------------
__global__ __launch_bounds__(256) void routing_kernel(
    const float* __restrict__ x, const float* __restrict__ noise,
    const float* __restrict__ mixer, const float* __restrict__ noisec,
    float* __restrict__ esc, int* __restrict__ counts, int* __restrict__ lists,
    float* __restrict__ out)
{
    __shared__ float xs[2 * 512];
    __shared__ float pm[2 * 2 * 64];   // [token][half][expert] mixer partials
    __shared__ float pn[2 * 2 * 64];
    const int blk  = blockIdx.x;       // tokens 2*blk, 2*blk+1
    const int tid  = threadIdx.x;
    const int wave = tid >> 6, lane = tid & 63;
    const int tq = wave >> 1;          // token 0/1
    const int ih = wave & 1;           // i half 0/1

    ((float4*)xs)[tid] = ((const float4*)x)[(size_t)blk * 256 + tid];
    // zero this block's two output rows (1024 floats = 256 float4)
    ((float4*)(out + (size_t)blk * 2 * OUT_W))[tid] = make_float4(0.f, 0.f, 0.f, 0.f);
    __syncthreads();

    float am = 0.f, an = 0.f;
    const float* xp = xs + tq * 512 + ih * 256;
    const float* mp = mixer  + (size_t)(ih * 256) * 64 + lane;
    const float* np = noisec + (size_t)(ih * 256) * 64 + lane;
    #pragma unroll 8
    for (int i = 0; i < 256; ++i) {
        const float xv = xp[i];                  // wave-uniform broadcast
        am = fmaf(xv, mp[i * 64], am);           // coalesced across lanes
        an = fmaf(xv, np[i * 64], an);
    }
    pm[tq * 128 + ih * 64 + lane] = am;
    pn[tq * 128 + ih * 64 + lane] = an;
    __syncthreads();

    if (tid < 128) {
        const int e = tid & 63, tt = tid >> 6;
        const int t = blk * 2 + tt;
        const float am2 = pm[tt * 128 + e] + pm[tt * 128 + 64 + e];
        const float an2 = pn[tt * 128 + e] + pn[tt * 128 + 64 + e];
        // softplus(v) = max(v,0) + log1p(exp(-|v|))
        const float sp = fmaxf(an2, 0.f) + log1pf(expf(-fabsf(an2)));
        pm[tt * 128 + e] = am2 + noise[(size_t)t * 64 + e] * sp;  // reuse as h
    }
    __syncthreads();

    if (tid < 2) {
        const float* h = pm + tid * 128;
        float b0 = -INFINITY, b1 = -INFINITY;
        int i0 = 0, i1 = 0;
        for (int i = 0; i < N_EXPERTS; ++i) {
            const float v = h[i];
            if (v > b0)      { b1 = b0; i1 = i0; b0 = v; i0 = i; }  // strict >: stable ties
            else if (v > b1) { b1 = v; i1 = i; }
        }
        const float z   = expf(b1 - b0);
        const float inv = 1.f / (1.f + z);
        const int t = blk * 2 + tid;
        esc[t * 2 + 0] = inv;
        esc[t * 2 + 1] = z * inv;
        const int p0 = atomicAdd(&counts[i0], 1);
        if (p0 < LIST_CAP) lists[i0 * LIST_CAP + p0] = t * 2 + 0;
        const int p1 = atomicAdd(&counts[i1], 1);
        if (p1 < LIST_CAP) lists[i1 * LIST_CAP + p1] = t * 2 + 1;
    }
}

// ---------------------------------------------------------------------------
// Fused expert FFN, v7 = round-1 compute structure (verified best, 53 us)
// with the weight stream moved to async global_load_lds double-buffering.
// Round 1-4 evidence: loop is ~15 us issue + ~38 us L2/L3 weight latency
// stall; register prefetch (r2/r3) and occupancy (r4) both fail on VGPR.
// global_load_lds costs no VGPRs; chunk k+1's DMA flies under chunk k's
// FMAs (minimum 2-phase pipeline). LDS weight reads are a column-slice
// (16-way bank conflict) -> XOR swizzle col^=(row&7), applied as: linear
// LDS dest + inverse-swizzled GLOBAL source + swizzled read (rule 21).
// ---------------------------------------------------------------------------
__device__ __forceinline__ void red_xor(float4& v, int m) {
    v.x += __shfl_xor(v.x, m); v.y += __shfl_xor(v.y, m);
    v.z += __shfl_xor(v.z, m); v.w += __shfl_xor(v.w, m);
}

__device__ __forceinline__ void fma4(float4& a, float s, const float4& w) {
    a.x = fmaf(s, w.x, a.x); a.y = fmaf(s, w.y, a.y);
    a.z = fmaf(s, w.z, a.z); a.w = fmaf(s, w.w, a.w);
}

// stage one 32 KB W1 chunk (32 rows x 256 cols): 2 x 16B per thread
__device__ __forceinline__ void stage_w1(const char* w1e, float* wlds, int buf,
                                         int k, int wave, int lane) {
    const char* gbase = w1e + (size_t)k * 32 * 1024;
    #pragma unroll
    for (int rr = 0; rr < 2; ++rr) {
        const int o  = rr * 16384 + wave * 1024 + lane * 16;  // chunk byte (this lane)
        const int r  = o >> 10;              // row 0..31
        const int cs = (o >> 4) & 63;        // stored col16
        const int c  = cs ^ (r & 7);         // logical col16 (inverse swizzle)
        const char* g = gbase + r * 1024 + c * 16;
        float* l = wlds + (size_t)buf * WCHUNK_FLOATS + (rr * 16384 + wave * 1024) / 4;
        __builtin_amdgcn_global_load_lds(
            (const __attribute__((address_space(1))) void*)g,
            (__attribute__((address_space(3))) void*)l, 16, 0, 0);
    }
}

// stage one 32 KB W2 chunk (16 rows x 512 cols): 2 x 16B per thread
__device__ __forceinline__ void stage_w2(const char* w2e, float* wlds, int buf,
                                         int k, int wave, int lane) {
    const char* gbase = w2e + (size_t)k * 16 * 2048;
    #pragma unroll
    for (int rr = 0; rr < 2; ++rr) {
        const int o  = rr * 16384 + wave * 1024 + lane * 16;
        const int r  = o >> 11;              // row 0..15
        const int cs = (o >> 4) & 127;       // stored col16
        const int c  = cs ^ (r & 7);         // logical col16
        const char* g = gbase + r * 2048 + c * 16;
        float* l = wlds + (size_t)buf * WCHUNK_FLOATS + (rr * 16384 + wave * 1024) / 4;
        __builtin_amdgcn_global_load_lds(
            (const __attribute__((address_space(1))) void*)g,
            (__attribute__((address_space(3))) void*)l, 16, 0, 0);
    }
}

template<int T>
__device__ __forceinline__ void run_pass(
    int nTok, int wave, int lane,
    const char* w1e, const char* w2e,
    const float4* __restrict__ b1v, const float4* __restrict__ b2v,
    const float* __restrict__ xs, float* __restrict__ vsm, float* __restrict__ wlds,
    const int* __restrict__ slotIds, const float* __restrict__ escv,
    float* __restrict__ out)
{
    const int c4l = lane & 3, r0 = lane >> 2;   // phase-1 roles
    const int c8  = lane & 7, r8 = lane >> 3;   // phase-2 roles

    // ---- phase 1: v = relu(x @ W1 + b1); W1 chunk = rows [k*32, k*32+32) ----
    {
        float4 acc[T];
        #pragma unroll
        for (int t = 0; t < T; ++t) acc[t] = make_float4(0.f, 0.f, 0.f, 0.f);
        const int swz = ((wave * 4 + c4l) ^ (r0 & 7)) * 4;   // swizzled col (floats)
        const float* xb = xs + r0;
        for (int k = 0; k < W1_NCHUNK; ++k) {
            if (k + 1 < W1_NCHUNK) stage_w1(w1e, wlds, (k + 1) & 1, k + 1, wave, lane);
            else                   stage_w2(w2e, wlds, 0, 0, wave, lane);  // phase-2 chunk 0
            const float* wb = wlds + (k & 1) * WCHUNK_FLOATS;
            const float4 wA = *(const float4*)&wb[r0 * 256 + swz];          // row r0
            const float4 wB = *(const float4*)&wb[(r0 + 16) * 256 + swz];   // row r0+16
            #pragma unroll
            for (int t = 0; t < T; ++t) {
                const float xvA = xb[t * XPAD + k * 32];
                const float xvB = xb[t * XPAD + k * 32 + 16];
                fma4(acc[t], xvA, wA);
                fma4(acc[t], xvB, wB);
            }
            __syncthreads();   // chunk k+1 landed; all reads of buf[k&1] done
        }
        #pragma unroll
        for (int t = 0; t < T; ++t) {      // reduce over r0 (lane bits 2..5)
            red_xor(acc[t], 4); red_xor(acc[t], 8);
            red_xor(acc[t], 16); red_xor(acc[t], 32);
        }
        if (r0 == 0) {
            const float4 bb = b1v[wave * 4 + c4l];
            #pragma unroll
            for (int t = 0; t < T; ++t) {
                float4 r;
                r.x = fmaxf(acc[t].x + bb.x, 0.f);
                r.y = fmaxf(acc[t].y + bb.y, 0.f);
                r.z = fmaxf(acc[t].z + bb.z, 0.f);
                r.w = fmaxf(acc[t].w + bb.w, 0.f);
                *(float4*)&vsm[t * VPAD + wave * 16 + c4l * 4] = r;
            }
        }
    }
    __syncthreads();   // vsm visible; W2 chunk 0 already resident in buf 0

    // ---- phase 2: out += sc*(v @ W2 + b2); W2 chunk = rows [k*16, k*16+16) ----
    {
        float4 acc[T];
        #pragma unroll
        for (int t = 0; t < T; ++t) acc[t] = make_float4(0.f, 0.f, 0.f, 0.f);
        const int swz2 = ((wave * 8 + c8) ^ r8) * 4;
        const float* vb = vsm + r8;
        for (int k = 0; k < W2_NCHUNK; ++k) {
            if (k + 1 < W2_NCHUNK) stage_w2(w2e, wlds, (k + 1) & 1, k + 1, wave, lane);
            const float* wb = wlds + (k & 1) * WCHUNK_FLOATS;
            const float4 wA = *(const float4*)&wb[r8 * 512 + swz2];        // row r8
            const float4 wB = *(const float4*)&wb[(r8 + 8) * 512 + swz2];  // row r8+8
            #pragma unroll
            for (int t = 0; t < T; ++t) {
                const float vA = vb[t * VPAD + k * 16];
                const float vB = vb[t * VPAD + k * 16 + 8];
                fma4(acc[t], vA, wA);
                fma4(acc[t], vB, wB);
            }
            __syncthreads();
        }
        #pragma unroll
        for (int t = 0; t < T; ++t) {      // reduce over r8 (lane bits 3..5)
            red_xor(acc[t], 8); red_xor(acc[t], 16); red_xor(acc[t], 32);
        }
        // butterfly leaves full sum in every lane; spread tokens over r8 groups
        const float4 bb = b2v[wave * 8 + c8];
        #pragma unroll
        for (int t = 0; t < T; ++t) {
            if ((t & 7) == r8 && t < nTok) {
                const float sc = escv[t];
                float* o = out + (size_t)(slotIds[t] >> 1) * OUT_W
                               + (wave * 8 + c8) * 4;
                atomicAdd(o + 0, (acc[t].x + bb.x) * sc);
                atomicAdd(o + 1, (acc[t].y + bb.y) * sc);
                atomicAdd(o + 2, (acc[t].z + bb.z) * sc);
                atomicAdd(o + 3, (acc[t].w + bb.w) * sc);
            }
        }
    }
}

__global__ __launch_bounds__(1024, 4) void expert_kernel(
    const float* __restrict__ x,
    const float* __restrict__ w1s, const float* __restrict__ b1s,
    const float* __restrict__ w2s, const float* __restrict__ b2s,
    const int* __restrict__ counts, const int* __restrict__ lists,
    const float* __restrict__ esc, float* __restrict__ out)
{
    __shared__ __align__(16) float xs[T_CAP * XPAD];         // 24.0 KB
    __shared__ __align__(16) float wlds[2 * WCHUNK_FLOATS];  // 64.0 KB dbuf
    __shared__ __align__(16) float vsm[T_CAP * VPAD];        // 12.0 KB
    __shared__ int   slotIds[T_CAP];
    __shared__ float escv[T_CAP];

    const int e  = blockIdx.x;
    const int g  = blockIdx.y;
    const int ne = min(counts[e], LIST_CAP);
    const int tid  = threadIdx.x;
    const int wave = tid >> 6, lane = tid & 63;

    const char* w1e = (const char*)(w1s + (size_t)e * IN_W * BLOCK_H);
    const char* w2e = (const char*)(w2s + (size_t)e * BLOCK_H * OUT_W);
    const float4* b1v = (const float4*)(b1s + (size_t)e * BLOCK_H);
    const float4* b2v = (const float4*)(b2s + (size_t)e * OUT_W);
    const float4* x4  = (const float4*)x;

    // pass p handles slot indices j = s0 + i*NGRP, i < T_CAP, s0 = g + p*48
    for (int s0 = g; s0 < ne; s0 += NGRP * T_CAP) {
        const int nTok  = min(T_CAP, (ne - s0 + NGRP - 1) / NGRP);
        const int Tpath = (nTok <= 4) ? 4 : (nTok <= 8) ? 8 : 12;

        if (tid < T_CAP) {
            int s = 0; float sc = 0.f;
            if (tid < nTok) { s = lists[e * LIST_CAP + s0 + tid * NGRP]; sc = esc[s]; }
            slotIds[tid] = s;
            escv[tid]    = sc;
        }
        __syncthreads();

        // issue W1 chunk-0 DMA, then stage token rows; one barrier drains both
        stage_w1(w1e, wlds, 0, 0, wave, lane);
        for (int idx = tid; idx < Tpath * 128; idx += 1024) {
            const int t = idx >> 7, q = idx & 127;
            float4 v = make_float4(0.f, 0.f, 0.f, 0.f);
            if (t < nTok) v = x4[(size_t)(slotIds[t] >> 1) * 128 + q];
            *(float4*)&xs[t * XPAD + q * 4] = v;
        }
        __syncthreads();

        if (nTok <= 4)
            run_pass<4>(nTok, wave, lane, w1e, w2e, b1v, b2v, xs, vsm, wlds, slotIds, escv, out);
        else if (nTok <= 8)
            run_pass<8>(nTok, wave, lane, w1e, w2e, b1v, b2v, xs, vsm, wlds, slotIds, escv, out);
        else
            run_pass<12>(nTok, wave, lane, w1e, w2e, b1v, b2v, xs, vsm, wlds, slotIds, escv, out);
        __syncthreads();   // xs/vsm/wlds reused next pass (rare: ne > 48)
    }
}

extern "C" void kernel_launch(void* const* d_in, const int* in_sizes, int n_in,
                              void* d_out, int out_size, void* d_ws, size_t ws_size,
                              hipStream_t stream) {
    const float* x      = (const float*)d_in[0];
    const float* noise  = (const float*)d_in[1];
    const float* w1s    = (const float*)d_in[2];
    const float* b1s    = (const float*)d_in[3];
    const float* w2s    = (const float*)d_in[4];
    const float* b2s    = (const float*)d_in[5];
    const float* mixer  = (const float*)d_in[6];
    const float* noisec = (const float*)d_in[7];
    float* out = (float*)d_out;

    // workspace: ~41 KB total (keep FAR under ws_size)
    char* ws = (char*)d_ws;
    int*   counts = (int*)ws;                       ws += 256;
    float* esc    = (float*)ws;                     ws += NSLOTS * sizeof(float);
    int*   lists  = (int*)ws;   /* 64 * 128 ints = 32 KB */

    hipMemsetAsync(counts, 0, 256, stream);

    routing_kernel<<<TOKENS / 2, 256, 0, stream>>>(x, noise, mixer, noisec,
                                                   esc, counts, lists, out);
    expert_kernel<<<dim3(N_EXPERTS, NGRP), 1024, 0, stream>>>(
        x, w1s, b1s, w2s, b2s, counts, lists, esc, out);
}